// Round 1
// baseline (67.459 us; speedup 1.0000x reference)
//
#include <hip/hip_runtime.h>

// ---------------- types / helpers ----------------
typedef short bf16x8 __attribute__((ext_vector_type(8)));
typedef float f32x4 __attribute__((ext_vector_type(4)));

#define NEGV -1000000000.0f
#define SCAN_CHUNK 8192

__device__ __forceinline__ unsigned short f2bf(float f) {
    unsigned int u = __float_as_uint(f);
    u += 0x7FFFu + ((u >> 16) & 1u);   // round-to-nearest-even
    return (unsigned short)(u >> 16);
}

// ---------------- prep: init + weight transpose/convert ----------------
__global__ void prep_kernel(const float* __restrict__ W1, const float* __restrict__ W2,
                            int* __restrict__ slot_node, int* __restrict__ counts,
                            unsigned short* __restrict__ w1t, unsigned short* __restrict__ w2t,
                            int nslots, int B) {
    int idx = blockIdx.x * 256 + threadIdx.x;
    if (idx < nslots) slot_node[idx] = -1;
    if (idx < B) counts[idx] = 0;
    if (idx < 128 * 256) {                 // W1T[col][k] = W1[k][col], bf16
        int col = idx >> 8, k = idx & 255;
        w1t[col * 256 + k] = f2bf(W1[k * 128 + col]);
    }
    if (idx < 32 * 128) {                  // W2T[col][k] = W2[k][col], pad col>=24 with 0
        int col = idx >> 7, k = idx & 127;
        w2t[col * 128 + k] = (col < 24) ? f2bf(W2[k * 24 + col]) : (unsigned short)0;
    }
}

// ---------------- scan pass 1: block partials + per-batch counts ----------------
__global__ void scan1_kernel(const int* __restrict__ mask, const int* __restrict__ batch,
                             int N, int* __restrict__ partials, int* __restrict__ counts) {
    int t = threadIdx.x;
    int base = blockIdx.x * SCAN_CHUNK + t * 32;
    int tsum = 0;
    int runb = -1, runc = 0;
    for (int j = 0; j < 32; ++j) {
        int i = base + j;
        if (i < N && mask[i]) {
            tsum++;
            int b = batch[i];
            if (b == runb) { runc++; }
            else { if (runc) atomicAdd(&counts[runb], runc); runb = b; runc = 1; }
        }
    }
    if (runc) atomicAdd(&counts[runb], runc);
    __shared__ int red[256];
    red[t] = tsum;
    __syncthreads();
    for (int s = 128; s > 0; s >>= 1) {
        if (t < s) red[t] += red[t + s];
        __syncthreads();
    }
    if (t == 0) partials[blockIdx.x] = red[0];
}

// ---------------- scan pass 2: single-block scans (counts->batchOfs, partials->blockOfs) ----
__global__ void scan2_kernel(const int* __restrict__ partials, int nblocks,
                             const int* __restrict__ counts, int B,
                             int* __restrict__ blockOfs, int* __restrict__ batchOfs) {
    __shared__ int buf[512];
    int t = threadIdx.x;
    int v = (t < B) ? counts[t] : 0;
    buf[t] = v; __syncthreads();
    for (int s = 1; s < 512; s <<= 1) {
        int add = (t >= s) ? buf[t - s] : 0;
        __syncthreads();
        buf[t] += add;
        __syncthreads();
    }
    if (t < B) batchOfs[t] = buf[t] - v;       // exclusive
    __syncthreads();
    int p = (t < nblocks) ? partials[t] : 0;
    buf[t] = p; __syncthreads();
    for (int s = 1; s < 512; s <<= 1) {
        int add = (t >= s) ? buf[t - s] : 0;
        __syncthreads();
        buf[t] += add;
        __syncthreads();
    }
    if (t < nblocks) blockOfs[t] = buf[t] - p; // exclusive
}

// ---------------- scan pass 3: scatter slot_node ----------------
__global__ void scan3_kernel(const int* __restrict__ mask, const int* __restrict__ batch,
                             int N, const int* __restrict__ blockOfs,
                             const int* __restrict__ batchOfs,
                             int* __restrict__ slot_node) {
    int t = threadIdx.x;
    int base = blockIdx.x * SCAN_CHUNK + t * 32;
    int tsum = 0;
    for (int j = 0; j < 32; ++j) {
        int i = base + j;
        if (i < N) tsum += (mask[i] != 0);
    }
    __shared__ int buf[256];
    buf[t] = tsum; __syncthreads();
    for (int s = 1; s < 256; s <<= 1) {
        int add = (t >= s) ? buf[t - s] : 0;
        __syncthreads();
        buf[t] += add;
        __syncthreads();
    }
    int excl = buf[t] - tsum + blockOfs[blockIdx.x];   // cubes strictly before my first elem
    for (int j = 0; j < 32; ++j) {
        int i = base + j;
        if (i < N && mask[i]) {
            int b = batch[i];
            int ci = excl - batchOfs[b];               // 0-based cube index within batch
            if (ci < 64) slot_node[b * 64 + ci] = i;
            excl++;
        }
    }
}

// ---------------- fused gather + MLP + scatter-out ----------------
// One block per batch b. 64 slots/block, 256 threads (4 waves).
// Layer1: [64x256]x[256x128] via mfma 16x16x32 bf16, BK=64 chunks.
// Layer2: [64x128]x[128x32(pad)] -> 24 moves.
__global__ void __launch_bounds__(256, 2)
mlp_kernel(const float* __restrict__ nf, const float* __restrict__ gf,
           const unsigned short* __restrict__ w1t, const unsigned short* __restrict__ w2t,
           const float* __restrict__ b1, const float* __restrict__ b2,
           const int* __restrict__ slot_node, const int* __restrict__ move_mask,
           float* __restrict__ out) {
    __shared__ __align__(16) unsigned short ldsA[64][72];    // A chunk: 64 rows x 64 k (pad 8)
    __shared__ __align__(16) unsigned short ldsB[128][72];   // W1T chunk: 128 cols x 64 k
    __shared__ __align__(16) unsigned short ldsH[64][136];   // hidden: 64 rows x 128 (pad 8)
    __shared__ __align__(16) unsigned short ldsW2[32][136];  // W2T: 32 cols x 128
    __shared__ int lds_node[64];

    int t = threadIdx.x;
    int blk = blockIdx.x;            // batch index
    int lane = t & 63, w = t >> 6;   // wave id 0..3

    if (t < 64) lds_node[t] = slot_node[blk * 64 + t];
    {   // stage W2T once: 32x128 bf16, 16 elems per thread
        int col = t >> 3;
        int k0 = (t & 7) * 16;
        const unsigned short* src = w2t + col * 128 + k0;
        *(bf16x8*)&ldsW2[col][k0]     = *(const bf16x8*)(src);
        *(bf16x8*)&ldsW2[col][k0 + 8] = *(const bf16x8*)(src + 8);
    }

    int wm = w >> 1, wn = w & 1;     // wave tile: rows [wm*32,+32), cols [wn*64,+64)
    f32x4 acc[2][4];
#pragma unroll
    for (int i = 0; i < 2; ++i)
#pragma unroll
        for (int j = 0; j < 4; ++j) acc[i][j] = (f32x4){0.f, 0.f, 0.f, 0.f};

    int r = t >> 2;                  // staging row 0..63
    int q = t & 3;                   // staging quarter (16 floats each)
    __syncthreads();                 // lds_node + ldsW2 ready
    int n = lds_node[r];
    bool valid = (n >= 0);

#pragma unroll
    for (int c = 0; c < 4; ++c) {
        {   // stage A chunk: k in [c*64, c*64+64); c<2 -> node_features, c>=2 -> global_features
            const float* src = (c < 2)
                ? nf + (size_t)(valid ? n : 0) * 128 + c * 64 + q * 16
                : gf + (size_t)blk * 128 + (c - 2) * 64 + q * 16;
            unsigned short tmp[16];
#pragma unroll
            for (int i = 0; i < 16; i += 4) {
                float4 f = valid ? *(const float4*)(src + i) : make_float4(0.f, 0.f, 0.f, 0.f);
                tmp[i] = f2bf(f.x); tmp[i + 1] = f2bf(f.y);
                tmp[i + 2] = f2bf(f.z); tmp[i + 3] = f2bf(f.w);
            }
            *(bf16x8*)&ldsA[r][q * 16]     = *(bf16x8*)&tmp[0];
            *(bf16x8*)&ldsA[r][q * 16 + 8] = *(bf16x8*)&tmp[8];
        }
        {   // stage W1T chunk: 128 cols x 64 k, 32 bf16 per thread
            int col = t >> 1;
            int h0 = (t & 1) * 32;
            const unsigned short* src = w1t + col * 256 + c * 64 + h0;
#pragma unroll
            for (int i = 0; i < 32; i += 8)
                *(bf16x8*)&ldsB[col][h0 + i] = *(const bf16x8*)(src + i);
        }
        __syncthreads();
#pragma unroll
        for (int ks = 0; ks < 2; ++ks) {
            int ko = ks * 32 + (lane >> 4) * 8;
            bf16x8 af[2], bfr[4];
#pragma unroll
            for (int mt = 0; mt < 2; ++mt)
                af[mt] = *(const bf16x8*)&ldsA[wm * 32 + mt * 16 + (lane & 15)][ko];
#pragma unroll
            for (int nt = 0; nt < 4; ++nt)
                bfr[nt] = *(const bf16x8*)&ldsB[wn * 64 + nt * 16 + (lane & 15)][ko];
#pragma unroll
            for (int mt = 0; mt < 2; ++mt)
#pragma unroll
                for (int nt = 0; nt < 4; ++nt)
                    acc[mt][nt] = __builtin_amdgcn_mfma_f32_16x16x32_bf16(
                        af[mt], bfr[nt], acc[mt][nt], 0, 0, 0);
        }
        __syncthreads();
    }

    // layer1 epilogue: bias + relu -> ldsH (bf16)
#pragma unroll
    for (int nt = 0; nt < 4; ++nt) {
        int col = wn * 64 + nt * 16 + (lane & 15);
        float bias = b1[col];
#pragma unroll
        for (int mt = 0; mt < 2; ++mt) {
            int row0 = wm * 32 + mt * 16 + (lane >> 4) * 4;
#pragma unroll
            for (int rr = 0; rr < 4; ++rr) {
                float v = acc[mt][nt][rr] + bias;
                v = v > 0.f ? v : 0.f;
                ldsH[row0 + rr][col] = f2bf(v);
            }
        }
    }
    __syncthreads();

    // layer2: wave w handles rows [w*16,+16); K=128 in 4 steps; 2 col-tiles (moves 0..31)
    f32x4 acc2[2];
    acc2[0] = (f32x4){0.f, 0.f, 0.f, 0.f};
    acc2[1] = (f32x4){0.f, 0.f, 0.f, 0.f};
#pragma unroll
    for (int ks = 0; ks < 4; ++ks) {
        int ko = ks * 32 + (lane >> 4) * 8;
        bf16x8 a2 = *(const bf16x8*)&ldsH[w * 16 + (lane & 15)][ko];
#pragma unroll
        for (int ct = 0; ct < 2; ++ct) {
            bf16x8 bw = *(const bf16x8*)&ldsW2[ct * 16 + (lane & 15)][ko];
            acc2[ct] = __builtin_amdgcn_mfma_f32_16x16x32_bf16(a2, bw, acc2[ct], 0, 0, 0);
        }
    }

    // write out: every (slot, m<24) element written exactly once
#pragma unroll
    for (int ct = 0; ct < 2; ++ct) {
        int m = ct * 16 + (lane & 15);
        if (m >= 24) continue;
        float bias = b2[m];
#pragma unroll
        for (int rr = 0; rr < 4; ++rr) {
            int row = w * 16 + (lane >> 4) * 4 + rr;
            int slot = blk * 64 + row;
            size_t oidx = (size_t)slot * 24 + m;
            float v = acc2[ct][rr] + bias;
            bool keep = (lds_node[row] >= 0) && (move_mask[oidx] != 0);
            out[oidx] = keep ? v : NEGV;
        }
    }
}

// ---------------- launcher ----------------
extern "C" void kernel_launch(void* const* d_in, const int* in_sizes, int n_in,
                              void* d_out, int out_size, void* d_ws, size_t ws_size,
                              hipStream_t stream) {
    const float* nf = (const float*)d_in[0];
    const float* gf = (const float*)d_in[1];
    const float* W1 = (const float*)d_in[2];
    const float* b1 = (const float*)d_in[3];
    const float* W2 = (const float*)d_in[4];
    const float* b2 = (const float*)d_in[5];
    const int* cube_mask = (const int*)d_in[6];
    const int* batch     = (const int*)d_in[7];
    const int* move_mask = (const int*)d_in[8];
    float* out = (float*)d_out;

    int N = in_sizes[6];            // 500000
    int B = in_sizes[1] / 128;      // 512
    int nslots = B * 64;            // 32768
    int NB = (N + SCAN_CHUNK - 1) / SCAN_CHUNK;   // 62

    char* ws = (char*)d_ws;
    int* slot_node = (int*)(ws);                      // nslots ints
    int* counts    = (int*)(ws + 131072);             // B
    int* batchOfs  = (int*)(ws + 133120);             // B
    int* partials  = (int*)(ws + 135168);             // NB (<=512)
    int* blockOfs  = (int*)(ws + 137216);             // NB
    unsigned short* w1t = (unsigned short*)(ws + 139264);  // 128*256 bf16
    unsigned short* w2t = (unsigned short*)(ws + 204800);  // 32*128 bf16

    prep_kernel<<<128, 256, 0, stream>>>(W1, W2, slot_node, counts, w1t, w2t, nslots, B);
    scan1_kernel<<<NB, 256, 0, stream>>>(cube_mask, batch, N, partials, counts);
    scan2_kernel<<<1, 512, 0, stream>>>(partials, NB, counts, B, blockOfs, batchOfs);
    scan3_kernel<<<NB, 256, 0, stream>>>(cube_mask, batch, N, blockOfs, batchOfs, slot_node);
    mlp_kernel<<<B, 256, 0, stream>>>(nf, gf, w1t, w2t, b1, b2, slot_node, move_mask, out);
    (void)n_in; (void)out_size; (void)ws_size;
}

// Round 2
// 20.152 us; speedup vs baseline: 3.3475x; 3.3475x over previous
//
#include <hip/hip_runtime.h>

// ---------------- types / helpers ----------------
typedef short bf16x8 __attribute__((ext_vector_type(8)));
typedef float f32x4 __attribute__((ext_vector_type(4)));

#define NEGV -1000000000.0f

__device__ __forceinline__ unsigned short f2bf(float f) {
    unsigned int u = __float_as_uint(f);
    u += 0x7FFFu + ((u >> 16) & 1u);   // round-to-nearest-even
    return (unsigned short)(u >> 16);
}

// ---------------- prep: batch segment boundaries + weight transpose ----------------
__global__ void prep_kernel(const float* __restrict__ W1, const float* __restrict__ W2,
                            const int* __restrict__ batch, int N, int B,
                            int* __restrict__ batch_start,
                            unsigned short* __restrict__ w1t, unsigned short* __restrict__ w2t) {
    int idx = blockIdx.x * 256 + threadIdx.x;
    if (idx < N) {
        int bcur = batch[idx];
        if (idx == 0) {
            for (int bb = 0; bb <= bcur; ++bb) batch_start[bb] = 0;
        } else {
            int bprev = batch[idx - 1];
            for (int bb = bprev + 1; bb <= bcur; ++bb) batch_start[bb] = idx;
        }
        if (idx == N - 1) {
            for (int bb = bcur + 1; bb <= B; ++bb) batch_start[bb] = N;
        }
    }
    if (idx < 128 * 256) {                 // W1T[col][k] = W1[k][col], bf16
        int col = idx >> 8, k = idx & 255;
        w1t[col * 256 + k] = f2bf(W1[k * 128 + col]);
    }
    if (idx < 32 * 128) {                  // W2T[col][k] = W2[k][col], pad col>=24 with 0
        int col = idx >> 7, k = idx & 127;
        w2t[col * 128 + k] = (col < 24) ? f2bf(W2[k * 24 + col]) : (unsigned short)0;
    }
}

// ---------------- fused: per-batch slot scan + gather + MLP + masked write ----------------
// One block per batch b (512 blocks, 256 threads = 4 waves).
// Phase 1: scan this batch's segment of cube_mask in 256-wide chunks, ballot-prefix,
//          record first 64 cube node ids into lds_node. Early exit.
// Phase 2: layer1 [64x256]x[256x128] via mfma 16x16x32 bf16 (BK=64, reg-prefetched),
//          layer2 [64x128]x[128x32pad] -> 24 moves, masked write.
__global__ void __launch_bounds__(256, 2)
fused_kernel(const float* __restrict__ nf, const float* __restrict__ gf,
             const unsigned short* __restrict__ w1t, const unsigned short* __restrict__ w2t,
             const float* __restrict__ b1, const float* __restrict__ b2,
             const int* __restrict__ cube_mask, const int* __restrict__ batch_start,
             const int* __restrict__ move_mask, float* __restrict__ out) {
    __shared__ __align__(16) unsigned short ldsA[64][72];    // A chunk: 64 rows x 64 k (pad 8)
    __shared__ __align__(16) unsigned short ldsB[128][72];   // W1T chunk: 128 cols x 64 k
    __shared__ __align__(16) unsigned short ldsH[64][136];   // hidden: 64 rows x 128 (pad 8)
    __shared__ __align__(16) unsigned short ldsW2[32][136];  // W2T: 32 cols x 128
    __shared__ int lds_node[64];
    __shared__ int wt[4];

    int t = threadIdx.x;
    int blk = blockIdx.x;            // batch index
    int lane = t & 63, w = t >> 6;   // wave id 0..3

    if (t < 64) lds_node[t] = -1;
    {   // stage W2T once: 32x128 bf16, 16 elems per thread
        int col = t >> 3;
        int k0 = (t & 7) * 16;
        const unsigned short* src = w2t + col * 128 + k0;
        *(bf16x8*)&ldsW2[col][k0]     = *(const bf16x8*)(src);
        *(bf16x8*)&ldsW2[col][k0 + 8] = *(const bf16x8*)(src + 8);
    }
    int segs = batch_start[blk], sege = batch_start[blk + 1];
    __syncthreads();                 // lds_node init + ldsW2 visible

    // ---- phase 1: find first 64 cubes in [segs, sege) ----
    int found = 0;
    for (int pos = segs; pos < sege && found < 64; pos += 256) {
        int i = pos + t;
        int m = (i < sege) ? cube_mask[i] : 0;
        unsigned long long bal = __ballot(m != 0);
        int below = __popcll(bal & ((1ULL << lane) - 1ULL));
        if (lane == 0) wt[w] = __popcll(bal);
        __syncthreads();
        int waveOfs = 0, total = 0;
#pragma unroll
        for (int j = 0; j < 4; ++j) { int c = wt[j]; if (j < w) waveOfs += c; total += c; }
        int rank = found + waveOfs + below;
        if (m && rank < 64) lds_node[rank] = i;
        found += total;
        __syncthreads();
    }
    __syncthreads();                 // lds_node final (loop exit is uniform)

    // ---- phase 2: MLP ----
    int wm = w >> 1, wn = w & 1;     // wave tile: rows [wm*32,+32), cols [wn*64,+64)
    f32x4 acc[2][4];
#pragma unroll
    for (int i = 0; i < 2; ++i)
#pragma unroll
        for (int j = 0; j < 4; ++j) acc[i][j] = (f32x4){0.f, 0.f, 0.f, 0.f};

    int r = t >> 2;                  // staging row 0..63
    int q = t & 3;                   // staging quarter (16 floats)
    int n = lds_node[r];
    int nrow = (n >= 0) ? n : 0;     // invalid rows read row 0; outputs masked at write

    float4 fA[4];                    // current A chunk regs (16 floats)
    bf16x8 fB[4];                    // current W1T chunk regs (32 bf16)
    int bcol = t >> 1;
    int bh0 = (t & 1) * 32;

#define LOAD_A(c) do { \
        const float* srcA = ((c) < 2) ? nf + (size_t)nrow * 128 + (c) * 64 + q * 16 \
                                      : gf + (size_t)blk * 128 + ((c) - 2) * 64 + q * 16; \
        fA[0] = *(const float4*)(srcA);      fA[1] = *(const float4*)(srcA + 4); \
        fA[2] = *(const float4*)(srcA + 8);  fA[3] = *(const float4*)(srcA + 12); \
    } while (0)
#define LOAD_B(c) do { \
        const unsigned short* srcB = w1t + bcol * 256 + (c) * 64 + bh0; \
        fB[0] = *(const bf16x8*)(srcB);      fB[1] = *(const bf16x8*)(srcB + 8); \
        fB[2] = *(const bf16x8*)(srcB + 16); fB[3] = *(const bf16x8*)(srcB + 24); \
    } while (0)

    LOAD_A(0); LOAD_B(0);
#pragma unroll
    for (int c = 0; c < 4; ++c) {
        {   // regs -> LDS
            unsigned short tmp[16];
#pragma unroll
            for (int i = 0; i < 4; ++i) {
                tmp[i * 4 + 0] = f2bf(fA[i].x); tmp[i * 4 + 1] = f2bf(fA[i].y);
                tmp[i * 4 + 2] = f2bf(fA[i].z); tmp[i * 4 + 3] = f2bf(fA[i].w);
            }
            *(bf16x8*)&ldsA[r][q * 16]     = *(bf16x8*)&tmp[0];
            *(bf16x8*)&ldsA[r][q * 16 + 8] = *(bf16x8*)&tmp[8];
            *(bf16x8*)&ldsB[bcol][bh0]      = fB[0];
            *(bf16x8*)&ldsB[bcol][bh0 + 8]  = fB[1];
            *(bf16x8*)&ldsB[bcol][bh0 + 16] = fB[2];
            *(bf16x8*)&ldsB[bcol][bh0 + 24] = fB[3];
        }
        __syncthreads();
        if (c < 3) { LOAD_A(c + 1); LOAD_B(c + 1); }   // prefetch next chunk over MFMA
#pragma unroll
        for (int ks = 0; ks < 2; ++ks) {
            int ko = ks * 32 + (lane >> 4) * 8;
            bf16x8 af[2], bfr[4];
#pragma unroll
            for (int mt = 0; mt < 2; ++mt)
                af[mt] = *(const bf16x8*)&ldsA[wm * 32 + mt * 16 + (lane & 15)][ko];
#pragma unroll
            for (int nt = 0; nt < 4; ++nt)
                bfr[nt] = *(const bf16x8*)&ldsB[wn * 64 + nt * 16 + (lane & 15)][ko];
#pragma unroll
            for (int mt = 0; mt < 2; ++mt)
#pragma unroll
                for (int nt = 0; nt < 4; ++nt)
                    acc[mt][nt] = __builtin_amdgcn_mfma_f32_16x16x32_bf16(
                        af[mt], bfr[nt], acc[mt][nt], 0, 0, 0);
        }
        __syncthreads();
    }
#undef LOAD_A
#undef LOAD_B

    // layer1 epilogue: bias + relu -> ldsH (bf16)
#pragma unroll
    for (int nt = 0; nt < 4; ++nt) {
        int col = wn * 64 + nt * 16 + (lane & 15);
        float bias = b1[col];
#pragma unroll
        for (int mt = 0; mt < 2; ++mt) {
            int row0 = wm * 32 + mt * 16 + (lane >> 4) * 4;
#pragma unroll
            for (int rr = 0; rr < 4; ++rr) {
                float v = acc[mt][nt][rr] + bias;
                v = v > 0.f ? v : 0.f;
                ldsH[row0 + rr][col] = f2bf(v);
            }
        }
    }
    __syncthreads();

    // layer2: wave w handles rows [w*16,+16); K=128 in 4 steps; cols 0..31 (pad of 24)
    f32x4 acc2[2];
    acc2[0] = (f32x4){0.f, 0.f, 0.f, 0.f};
    acc2[1] = (f32x4){0.f, 0.f, 0.f, 0.f};
#pragma unroll
    for (int ks = 0; ks < 4; ++ks) {
        int ko = ks * 32 + (lane >> 4) * 8;
        bf16x8 a2 = *(const bf16x8*)&ldsH[w * 16 + (lane & 15)][ko];
#pragma unroll
        for (int ct = 0; ct < 2; ++ct) {
            bf16x8 bw = *(const bf16x8*)&ldsW2[ct * 16 + (lane & 15)][ko];
            acc2[ct] = __builtin_amdgcn_mfma_f32_16x16x32_bf16(a2, bw, acc2[ct], 0, 0, 0);
        }
    }

    // write out: every (slot, m<24) element written exactly once per call
#pragma unroll
    for (int ct = 0; ct < 2; ++ct) {
        int m = ct * 16 + (lane & 15);
        if (m >= 24) continue;
        float bias = b2[m];
#pragma unroll
        for (int rr = 0; rr < 4; ++rr) {
            int row = w * 16 + (lane >> 4) * 4 + rr;
            int slot = blk * 64 + row;
            size_t oidx = (size_t)slot * 24 + m;
            float v = acc2[ct][rr] + bias;
            bool keep = (lds_node[row] >= 0) && (move_mask[oidx] != 0);
            out[oidx] = keep ? v : NEGV;
        }
    }
}

// ---------------- launcher ----------------
extern "C" void kernel_launch(void* const* d_in, const int* in_sizes, int n_in,
                              void* d_out, int out_size, void* d_ws, size_t ws_size,
                              hipStream_t stream) {
    const float* nf = (const float*)d_in[0];
    const float* gf = (const float*)d_in[1];
    const float* W1 = (const float*)d_in[2];
    const float* b1 = (const float*)d_in[3];
    const float* W2 = (const float*)d_in[4];
    const float* b2 = (const float*)d_in[5];
    const int* cube_mask = (const int*)d_in[6];
    const int* batch     = (const int*)d_in[7];
    const int* move_mask = (const int*)d_in[8];
    float* out = (float*)d_out;

    int N = in_sizes[6];            // 500000
    int B = in_sizes[1] / 128;      // 512

    char* ws = (char*)d_ws;
    int* batch_start = (int*)(ws);                         // B+1 ints
    unsigned short* w1t = (unsigned short*)(ws + 4096);    // 128*256 bf16 (64 KB)
    unsigned short* w2t = (unsigned short*)(ws + 69632);   // 32*128 bf16 (8 KB)

    int NB = (N + 255) / 256;       // 1954
    prep_kernel<<<NB, 256, 0, stream>>>(W1, W2, batch, N, B, batch_start, w1t, w2t);
    fused_kernel<<<B, 256, 0, stream>>>(nf, gf, w1t, w2t, b1, b2,
                                        cube_mask, batch_start, move_mask, out);
    (void)n_in; (void)out_size; (void)ws_size;
}

// Round 3
// 17.909 us; speedup vs baseline: 3.7668x; 1.1253x over previous
//
#include <hip/hip_runtime.h>

// ---------------- types / helpers ----------------
typedef short bf16x8 __attribute__((ext_vector_type(8)));
typedef float f32x4 __attribute__((ext_vector_type(4)));

#define NEGV -1000000000.0f

__device__ __forceinline__ unsigned short f2bf(float f) {
    unsigned int u = __float_as_uint(f);
    u += 0x7FFFu + ((u >> 16) & 1u);   // round-to-nearest-even
    return (unsigned short)(u >> 16);
}

// ---------------- prep: batch segment boundaries + weight transpose ----------------
__global__ void prep_kernel(const float* __restrict__ W1, const float* __restrict__ W2,
                            const int* __restrict__ batch, int N, int B,
                            int* __restrict__ batch_start,
                            unsigned short* __restrict__ w1t, unsigned short* __restrict__ w2t) {
    int idx = blockIdx.x * 256 + threadIdx.x;
    if (idx < N) {
        int bcur = batch[idx];
        if (idx == 0) {
            for (int bb = 0; bb <= bcur; ++bb) batch_start[bb] = 0;
        } else {
            int bprev = batch[idx - 1];
            for (int bb = bprev + 1; bb <= bcur; ++bb) batch_start[bb] = idx;
        }
        if (idx == N - 1) {
            for (int bb = bcur + 1; bb <= B; ++bb) batch_start[bb] = N;
        }
    }
    if (idx < 128 * 256) {                 // W1T[col][k] = W1[k][col], bf16
        int col = idx >> 8, k = idx & 255;
        w1t[col * 256 + k] = f2bf(W1[k * 128 + col]);
    }
    if (idx < 32 * 128) {                  // W2T[col][k] = W2[k][col], pad col>=24 with 0
        int col = idx >> 7, k = idx & 127;
        w2t[col * 128 + k] = (col < 24) ? f2bf(W2[k * 24 + col]) : (unsigned short)0;
    }
}

// ---------------- fused: per-batch slot scan + gather + MLP + masked write ----------------
// One block per batch b (512 blocks, 256 threads = 4 waves, 3 blocks/CU).
// ldsH aliases ldsA/ldsB (dead after the K-loop) to cut LDS 54->37 KB.
__global__ void __launch_bounds__(256, 3)
fused_kernel(const float* __restrict__ nf, const float* __restrict__ gf,
             const unsigned short* __restrict__ w1t, const unsigned short* __restrict__ w2t,
             const float* __restrict__ b1, const float* __restrict__ b2,
             const int* __restrict__ cube_mask, const int* __restrict__ batch_start,
             const int* __restrict__ move_mask, float* __restrict__ out) {
    __shared__ __align__(16) char smemAB[(64 * 72 + 128 * 72) * 2];   // ldsA | ldsB, aliased by ldsH
    __shared__ __align__(16) unsigned short ldsW2[32][136];
    __shared__ int lds_node[64];
    __shared__ int wt[4];
    unsigned short (*ldsA)[72]  = (unsigned short (*)[72])smemAB;
    unsigned short (*ldsB)[72]  = (unsigned short (*)[72])(smemAB + 64 * 72 * 2);
    unsigned short (*ldsH)[136] = (unsigned short (*)[136])smemAB;

    int t = threadIdx.x;
    int blk = blockIdx.x;            // batch index
    int lane = t & 63, w = t >> 6;   // wave id 0..3

    // ---- dependent chain head: issue ASAP ----
    int segs = batch_start[blk], sege = batch_start[blk + 1];

    if (t < 64) lds_node[t] = -1;

    // ---- independent prefetches (overlap the phase-1 latency chain) ----
    {   // stage W2T once: 32x128 bf16, 16 elems per thread
        int col = t >> 3;
        int k0 = (t & 7) * 16;
        const unsigned short* src = w2t + col * 128 + k0;
        *(bf16x8*)&ldsW2[col][k0]     = *(const bf16x8*)(src);
        *(bf16x8*)&ldsW2[col][k0 + 8] = *(const bf16x8*)(src + 8);
    }
    int bcol = t >> 1, bh0 = (t & 1) * 32;
    bf16x8 fB[4];
    {   // W1T chunk 0 into regs
        const unsigned short* srcB = w1t + bcol * 256 + bh0;
        fB[0] = *(const bf16x8*)(srcB);      fB[1] = *(const bf16x8*)(srcB + 8);
        fB[2] = *(const bf16x8*)(srcB + 16); fB[3] = *(const bf16x8*)(srcB + 24);
    }
    int wm = w >> 1, wn = w & 1;     // wave tile: rows [wm*32,+32), cols [wn*64,+64)
    float b1v[4];
#pragma unroll
    for (int nt = 0; nt < 4; ++nt) b1v[nt] = b1[wn * 64 + nt * 16 + (lane & 15)];
    float b2v[2];
    int mmv[8];
#pragma unroll
    for (int ct = 0; ct < 2; ++ct) {
        int m = ct * 16 + (lane & 15);
        if (m < 24) {
            b2v[ct] = b2[m];
#pragma unroll
            for (int rr = 0; rr < 4; ++rr) {
                int row = w * 16 + (lane >> 4) * 4 + rr;
                mmv[ct * 4 + rr] = move_mask[(size_t)(blk * 64 + row) * 24 + m];
            }
        } else {
            b2v[ct] = 0.f;
#pragma unroll
            for (int rr = 0; rr < 4; ++rr) mmv[ct * 4 + rr] = 0;
        }
    }
    __syncthreads();                 // lds_node init + ldsW2 visible

    // ---- phase 1: find first 64 cubes in [segs, sege) ----
    int found = 0;
    for (int pos = segs; pos < sege && found < 64; pos += 256) {
        int i = pos + t;
        int m = (i < sege) ? cube_mask[i] : 0;
        unsigned long long bal = __ballot(m != 0);
        int below = __popcll(bal & ((1ULL << lane) - 1ULL));
        if (lane == 0) wt[w] = __popcll(bal);
        __syncthreads();
        int waveOfs = 0, total = 0;
#pragma unroll
        for (int j = 0; j < 4; ++j) { int c = wt[j]; if (j < w) waveOfs += c; total += c; }
        int rank = found + waveOfs + below;
        if (m && rank < 64) lds_node[rank] = i;
        found += total;
        __syncthreads();
    }

    // ---- phase 2: MLP ----
    int r = t >> 2;                  // staging row 0..63
    int q = t & 3;                   // staging quarter (16 floats)
    int n = lds_node[r];
    int nrow = (n >= 0) ? n : 0;     // invalid rows read row 0; outputs masked at write

    // issue the whole nf row segment for this thread now (chunks 0 and 1): one gather latency
    const float* srcN = nf + (size_t)nrow * 128 + q * 16;
    float4 fN[8];
#pragma unroll
    for (int i = 0; i < 4; ++i) {
        fN[i]     = *(const float4*)(srcN + i * 4);
        fN[4 + i] = *(const float4*)(srcN + 64 + i * 4);
    }

    f32x4 acc[2][4];
#pragma unroll
    for (int i = 0; i < 2; ++i)
#pragma unroll
        for (int j = 0; j < 4; ++j) acc[i][j] = (f32x4){0.f, 0.f, 0.f, 0.f};

    float4 fA[4];                    // gf prefetch window (chunks 2,3)

#pragma unroll
    for (int c = 0; c < 4; ++c) {
        {   // regs -> LDS (A)
            float4 s0 = (c == 0) ? fN[0] : (c == 1) ? fN[4] : fA[0];
            float4 s1 = (c == 0) ? fN[1] : (c == 1) ? fN[5] : fA[1];
            float4 s2 = (c == 0) ? fN[2] : (c == 1) ? fN[6] : fA[2];
            float4 s3 = (c == 0) ? fN[3] : (c == 1) ? fN[7] : fA[3];
            unsigned short tmp[16];
            tmp[0]  = f2bf(s0.x); tmp[1]  = f2bf(s0.y); tmp[2]  = f2bf(s0.z); tmp[3]  = f2bf(s0.w);
            tmp[4]  = f2bf(s1.x); tmp[5]  = f2bf(s1.y); tmp[6]  = f2bf(s1.z); tmp[7]  = f2bf(s1.w);
            tmp[8]  = f2bf(s2.x); tmp[9]  = f2bf(s2.y); tmp[10] = f2bf(s2.z); tmp[11] = f2bf(s2.w);
            tmp[12] = f2bf(s3.x); tmp[13] = f2bf(s3.y); tmp[14] = f2bf(s3.z); tmp[15] = f2bf(s3.w);
            *(bf16x8*)&ldsA[r][q * 16]     = *(bf16x8*)&tmp[0];
            *(bf16x8*)&ldsA[r][q * 16 + 8] = *(bf16x8*)&tmp[8];
            // regs -> LDS (B)
            *(bf16x8*)&ldsB[bcol][bh0]      = fB[0];
            *(bf16x8*)&ldsB[bcol][bh0 + 8]  = fB[1];
            *(bf16x8*)&ldsB[bcol][bh0 + 16] = fB[2];
            *(bf16x8*)&ldsB[bcol][bh0 + 24] = fB[3];
        }
        __syncthreads();
        if (c < 3) {                 // prefetch next W1T chunk
            const unsigned short* srcB = w1t + bcol * 256 + (c + 1) * 64 + bh0;
            fB[0] = *(const bf16x8*)(srcB);      fB[1] = *(const bf16x8*)(srcB + 8);
            fB[2] = *(const bf16x8*)(srcB + 16); fB[3] = *(const bf16x8*)(srcB + 24);
        }
        if (c == 1 || c == 2) {      // prefetch gf chunk (c+1 in {2,3})
            const float* srcG = gf + (size_t)blk * 128 + (c - 1) * 64 + q * 16;
            fA[0] = *(const float4*)(srcG);     fA[1] = *(const float4*)(srcG + 4);
            fA[2] = *(const float4*)(srcG + 8); fA[3] = *(const float4*)(srcG + 12);
        }
#pragma unroll
        for (int ks = 0; ks < 2; ++ks) {
            int ko = ks * 32 + (lane >> 4) * 8;
            bf16x8 af[2], bfr[4];
#pragma unroll
            for (int mt = 0; mt < 2; ++mt)
                af[mt] = *(const bf16x8*)&ldsA[wm * 32 + mt * 16 + (lane & 15)][ko];
#pragma unroll
            for (int nt = 0; nt < 4; ++nt)
                bfr[nt] = *(const bf16x8*)&ldsB[wn * 64 + nt * 16 + (lane & 15)][ko];
#pragma unroll
            for (int mt = 0; mt < 2; ++mt)
#pragma unroll
                for (int nt = 0; nt < 4; ++nt)
                    acc[mt][nt] = __builtin_amdgcn_mfma_f32_16x16x32_bf16(
                        af[mt], bfr[nt], acc[mt][nt], 0, 0, 0);
        }
        __syncthreads();
    }

    // layer1 epilogue: bias + relu -> ldsH (aliases ldsA/ldsB, which are dead now)
#pragma unroll
    for (int nt = 0; nt < 4; ++nt) {
        int col = wn * 64 + nt * 16 + (lane & 15);
        float bias = b1v[nt];
#pragma unroll
        for (int mt = 0; mt < 2; ++mt) {
            int row0 = wm * 32 + mt * 16 + (lane >> 4) * 4;
#pragma unroll
            for (int rr = 0; rr < 4; ++rr) {
                float v = acc[mt][nt][rr] + bias;
                v = v > 0.f ? v : 0.f;
                ldsH[row0 + rr][col] = f2bf(v);
            }
        }
    }
    __syncthreads();

    // layer2: wave w handles rows [w*16,+16); K=128 in 4 steps; cols 0..31 (pad of 24)
    f32x4 acc2[2];
    acc2[0] = (f32x4){0.f, 0.f, 0.f, 0.f};
    acc2[1] = (f32x4){0.f, 0.f, 0.f, 0.f};
#pragma unroll
    for (int ks = 0; ks < 4; ++ks) {
        int ko = ks * 32 + (lane >> 4) * 8;
        bf16x8 a2 = *(const bf16x8*)&ldsH[w * 16 + (lane & 15)][ko];
#pragma unroll
        for (int ct = 0; ct < 2; ++ct) {
            bf16x8 bw = *(const bf16x8*)&ldsW2[ct * 16 + (lane & 15)][ko];
            acc2[ct] = __builtin_amdgcn_mfma_f32_16x16x32_bf16(a2, bw, acc2[ct], 0, 0, 0);
        }
    }

    // write out: every (slot, m<24) element written exactly once per call
#pragma unroll
    for (int ct = 0; ct < 2; ++ct) {
        int m = ct * 16 + (lane & 15);
        if (m >= 24) continue;
#pragma unroll
        for (int rr = 0; rr < 4; ++rr) {
            int row = w * 16 + (lane >> 4) * 4 + rr;
            size_t oidx = (size_t)(blk * 64 + row) * 24 + m;
            float v = acc2[ct][rr] + b2v[ct];
            bool keep = (lds_node[row] >= 0) && (mmv[ct * 4 + rr] != 0);
            out[oidx] = keep ? v : NEGV;
        }
    }
}

// ---------------- launcher ----------------
extern "C" void kernel_launch(void* const* d_in, const int* in_sizes, int n_in,
                              void* d_out, int out_size, void* d_ws, size_t ws_size,
                              hipStream_t stream) {
    const float* nf = (const float*)d_in[0];
    const float* gf = (const float*)d_in[1];
    const float* W1 = (const float*)d_in[2];
    const float* b1 = (const float*)d_in[3];
    const float* W2 = (const float*)d_in[4];
    const float* b2 = (const float*)d_in[5];
    const int* cube_mask = (const int*)d_in[6];
    const int* batch     = (const int*)d_in[7];
    const int* move_mask = (const int*)d_in[8];
    float* out = (float*)d_out;

    int N = in_sizes[6];            // 500000
    int B = in_sizes[1] / 128;      // 512

    char* ws = (char*)d_ws;
    int* batch_start = (int*)(ws);                         // B+1 ints
    unsigned short* w1t = (unsigned short*)(ws + 4096);    // 128*256 bf16 (64 KB)
    unsigned short* w2t = (unsigned short*)(ws + 69632);   // 32*128 bf16 (8 KB)

    int NB = (N + 255) / 256;       // 1954
    prep_kernel<<<NB, 256, 0, stream>>>(W1, W2, batch, N, B, batch_start, w1t, w2t);
    fused_kernel<<<B, 256, 0, stream>>>(nf, gf, w1t, w2t, b1, b2,
                                        cube_mask, batch_start, move_mask, out);
    (void)n_in; (void)out_size; (void)ws_size;
}